// Round 11
// baseline (480.387 us; speedup 1.0000x reference)
//
#include <hip/hip_runtime.h>

typedef short s16x8 __attribute__((ext_vector_type(8)));   // 8 bf16 = 4 VGPRs
typedef float fx4 __attribute__((ext_vector_type(4)));     // MFMA acc

#define AS_G(p) ((const __attribute__((address_space(1))) void*)(p))
#define AS_L(p) ((__attribute__((address_space(3))) void*)(p))

__device__ inline unsigned short f32_to_bf16(float f) {
    unsigned int u = __float_as_uint(f);
    return (unsigned short)((u + 0x7fffu + ((u >> 16) & 1u)) >> 16);
}
__device__ inline float bf16_to_f32(unsigned short b) {
    return __uint_as_float(((unsigned int)b) << 16);
}
__device__ inline void split2(float a, unsigned short& hi, unsigned short& lo) {
    hi = f32_to_bf16(a);
    lo = f32_to_bf16(a - bf16_to_f32(hi));
}

// ===================== graph preprocessing =====================

__global__ void k_deg(const int* __restrict__ dst, int E, int* __restrict__ deg) {
    int i = blockIdx.x * blockDim.x + threadIdx.x;
    if (i < E) atomicAdd(&deg[dst[i]], 1);
}

// fused dispatch: blocks [0,nb) do deg-scan + dinv; blocks [nb, nb+wb) do weight split/transpose.
__global__ void k_scan1w(const int* __restrict__ deg, int N, int nb,
                         int* __restrict__ part, int* __restrict__ bsum, float* __restrict__ dinv,
                         const float* __restrict__ W0, unsigned short* __restrict__ h0, unsigned short* __restrict__ l0,
                         const float* __restrict__ W1, unsigned short* __restrict__ h1, unsigned short* __restrict__ l1,
                         const float* __restrict__ W2, unsigned short* __restrict__ h2, unsigned short* __restrict__ l2,
                         int DIN, int DH) {
    __shared__ int s[256];
    if (blockIdx.x < (unsigned)nb) {
        int i = blockIdx.x * 256 + threadIdx.x;
        int v = (i < N) ? deg[i] : 0;
        if (i < N) dinv[i] = 1.0f / sqrtf((float)(v + 1));  // +1 self-loop
        s[threadIdx.x] = v;
        __syncthreads();
        for (int off = 1; off < 256; off <<= 1) {
            int t = (threadIdx.x >= off) ? s[threadIdx.x - off] : 0;
            __syncthreads();
            s[threadIdx.x] += t;
            __syncthreads();
        }
        if (i < N) part[i] = s[threadIdx.x] - v;
        if (threadIdx.x == 255) bsum[blockIdx.x] = s[255];
    } else {
        int i = (blockIdx.x - nb) * 256 + threadIdx.x;
        const int n0 = DIN * DH, n1 = DH * DH;
        const float* W; unsigned short *hT, *lT; int K, li;
        if (i < n0) { W = W0; hT = h0; lT = l0; K = DIN; li = i; }
        else if (i < n0 + n1) { W = W1; hT = h1; lT = l1; K = DH; li = i - n0; }
        else if (i < n0 + 2 * n1) { W = W2; hT = h2; lT = l2; K = DH; li = i - n0 - n1; }
        else return;
        int k = li / DH, n = li - k * DH;
        unsigned short h, l;
        split2(W[li], h, l);
        hT[(size_t)n * K + k] = h;
        lT[(size_t)n * K + k] = l;
    }
}

// fused: scan of block sums + graph-boundary binary search over sorted batch
__global__ void k_scan2(int* __restrict__ bsum, int nb,
                        const int* __restrict__ batch, int N, int ngraphs, int* __restrict__ gstart) {
    int g = threadIdx.x;
    if (g <= ngraphs) {
        if (g == ngraphs) gstart[g] = N;
        else {
            int lo = 0, hi = N;
            while (lo < hi) {
                int mid = (lo + hi) >> 1;
                if (batch[mid] < g) lo = mid + 1; else hi = mid;
            }
            gstart[g] = lo;
        }
    }
    __shared__ int s[256];
    int v = (threadIdx.x < nb) ? bsum[threadIdx.x] : 0;
    s[threadIdx.x] = v;
    __syncthreads();
    for (int off = 1; off < 256; off <<= 1) {
        int t = (threadIdx.x >= off) ? s[threadIdx.x - off] : 0;
        __syncthreads();
        s[threadIdx.x] += t;
        __syncthreads();
    }
    if (threadIdx.x < nb) bsum[threadIdx.x] = s[threadIdx.x] - v;
}

__global__ void k_scan3(const int* __restrict__ part, const int* __restrict__ bsum, int N, int E,
                        int* __restrict__ rowptr, int* __restrict__ cursor) {
    int i = blockIdx.x * 256 + threadIdx.x;
    if (i < N) {
        int v = part[i] + bsum[blockIdx.x];
        rowptr[i] = v;
        cursor[i] = v;
    }
    if (i == 0) rowptr[N] = E;
}

__global__ void k_fill(const int* __restrict__ src, const int* __restrict__ dst, int E,
                       const float* __restrict__ dinv, int* __restrict__ cursor,
                       int* __restrict__ col, float* __restrict__ nrm) {
    int e = blockIdx.x * blockDim.x + threadIdx.x;
    if (e < E) {
        int s = src[e], d = dst[e];
        int p = atomicAdd(&cursor[d], 1);
        col[p] = s;
        nrm[p] = dinv[s] * dinv[d];
    }
}

// ===================== split-bf16 MFMA GEMM + fused bias/ReLU =====================

__global__ __launch_bounds__(256) void k_gemm_mfma(
    const unsigned short* __restrict__ Ahi, const unsigned short* __restrict__ Alo,
    const unsigned short* __restrict__ BhiT, const unsigned short* __restrict__ BloT,
    const float* __restrict__ bias, float* __restrict__ C, int Nrows, int K) {
    __shared__ __align__(16) unsigned short sAhi[128 * 32];
    __shared__ __align__(16) unsigned short sAlo[128 * 32];
    __shared__ __align__(16) unsigned short sBhi[128 * 32];
    __shared__ __align__(16) unsigned short sBlo[128 * 32];

    const int tid = threadIdx.x;
    const int wid = tid >> 6, lane = tid & 63;
    const int row0 = blockIdx.y * 128;
    const int col0 = blockIdx.x * 128;
    const int wrow = wid & 1, wcol = wid >> 1;
    const int quad = lane >> 4, l16 = lane & 15;

    const unsigned short* garr = (wid == 0) ? Ahi : (wid == 1) ? Alo : (wid == 2) ? BhiT : BloT;
    unsigned short* sarr = (wid == 0) ? sAhi : (wid == 1) ? sAlo : (wid == 2) ? sBhi : sBlo;
    const bool isA = (wid < 2);

    const unsigned short* gp[8];
#pragma unroll
    for (int i = 0; i < 8; ++i) {
        int r = 16 * i + (lane >> 2);
        int s = lane & 3;
        int q = (s - (r >> 1)) & 3;              // XOR bank-swizzle in global address
        int grow = isA ? min(row0 + r, Nrows - 1) : (col0 + r);
        gp[i] = garr + (size_t)grow * K + q * 8;
    }

    int aidx[4], bidx[4];
#pragma unroll
    for (int t = 0; t < 4; ++t) {
        int ra = wrow * 64 + t * 16 + l16;
        aidx[t] = ra * 32 + ((quad + (ra >> 1)) & 3) * 8;
        int rb = wcol * 64 + t * 16 + l16;
        bidx[t] = rb * 32 + ((quad + (rb >> 1)) & 3) * 8;
    }

    fx4 acc[4][4] = {};

    for (int k0 = 0; k0 < K; k0 += 32) {
#pragma unroll
        for (int i = 0; i < 8; ++i)
            __builtin_amdgcn_global_load_lds(AS_G(gp[i] + k0), AS_L((char*)sarr + i * 1024), 16, 0, 0);
        __syncthreads();

        s16x8 ah[4], al[4];
#pragma unroll
        for (int mi = 0; mi < 4; ++mi) {
            ah[mi] = *(const s16x8*)&sAhi[aidx[mi]];
            al[mi] = *(const s16x8*)&sAlo[aidx[mi]];
        }
#pragma unroll
        for (int nj = 0; nj < 4; ++nj) {
            s16x8 bh = *(const s16x8*)&sBhi[bidx[nj]];
            s16x8 bl = *(const s16x8*)&sBlo[bidx[nj]];
#pragma unroll
            for (int mi = 0; mi < 4; ++mi) {
                acc[mi][nj] = __builtin_amdgcn_mfma_f32_16x16x32_bf16(ah[mi], bh, acc[mi][nj], 0, 0, 0);
                acc[mi][nj] = __builtin_amdgcn_mfma_f32_16x16x32_bf16(ah[mi], bl, acc[mi][nj], 0, 0, 0);
                acc[mi][nj] = __builtin_amdgcn_mfma_f32_16x16x32_bf16(al[mi], bh, acc[mi][nj], 0, 0, 0);
            }
        }
        __syncthreads();
    }

#pragma unroll
    for (int mi = 0; mi < 4; ++mi) {
        const int rbase = row0 + wrow * 64 + mi * 16 + quad * 4;
#pragma unroll
        for (int nj = 0; nj < 4; ++nj) {
            const int c = col0 + wcol * 64 + nj * 16 + l16;
            const float bc = bias[c];
#pragma unroll
            for (int reg = 0; reg < 4; ++reg) {
                int r = rbase + reg;
                if (r < Nrows) C[(size_t)r * 256 + c] = fmaxf(acc[mi][nj][reg] + bc, 0.f);
            }
        }
    }
}

// Layer-2 variant: relu(acc+bias) pooled per-graph into gsum[64][256] via segment
// reduction + cross-quad shfl + atomicAdd (batch sorted => few segments per tile).
__global__ __launch_bounds__(256) void k_gemm_pool(
    const unsigned short* __restrict__ Ahi, const unsigned short* __restrict__ Alo,
    const unsigned short* __restrict__ BhiT, const unsigned short* __restrict__ BloT,
    const float* __restrict__ bias, const int* __restrict__ batch,
    float* __restrict__ gsum, int Nrows, int K) {
    __shared__ __align__(16) unsigned short sAhi[128 * 32];
    __shared__ __align__(16) unsigned short sAlo[128 * 32];
    __shared__ __align__(16) unsigned short sBhi[128 * 32];
    __shared__ __align__(16) unsigned short sBlo[128 * 32];

    const int tid = threadIdx.x;
    const int wid = tid >> 6, lane = tid & 63;
    const int row0 = blockIdx.y * 128;
    const int col0 = blockIdx.x * 128;
    const int wrow = wid & 1, wcol = wid >> 1;
    const int quad = lane >> 4, l16 = lane & 15;

    const unsigned short* garr = (wid == 0) ? Ahi : (wid == 1) ? Alo : (wid == 2) ? BhiT : BloT;
    unsigned short* sarr = (wid == 0) ? sAhi : (wid == 1) ? sAlo : (wid == 2) ? sBhi : sBlo;
    const bool isA = (wid < 2);

    const unsigned short* gp[8];
#pragma unroll
    for (int i = 0; i < 8; ++i) {
        int r = 16 * i + (lane >> 2);
        int s = lane & 3;
        int q = (s - (r >> 1)) & 3;
        int grow = isA ? min(row0 + r, Nrows - 1) : (col0 + r);
        gp[i] = garr + (size_t)grow * K + q * 8;
    }

    int aidx[4], bidx[4];
#pragma unroll
    for (int t = 0; t < 4; ++t) {
        int ra = wrow * 64 + t * 16 + l16;
        aidx[t] = ra * 32 + ((quad + (ra >> 1)) & 3) * 8;
        int rb = wcol * 64 + t * 16 + l16;
        bidx[t] = rb * 32 + ((quad + (rb >> 1)) & 3) * 8;
    }

    fx4 acc[4][4] = {};

    for (int k0 = 0; k0 < K; k0 += 32) {
#pragma unroll
        for (int i = 0; i < 8; ++i)
            __builtin_amdgcn_global_load_lds(AS_G(gp[i] + k0), AS_L((char*)sarr + i * 1024), 16, 0, 0);
        __syncthreads();

        s16x8 ah[4], al[4];
#pragma unroll
        for (int mi = 0; mi < 4; ++mi) {
            ah[mi] = *(const s16x8*)&sAhi[aidx[mi]];
            al[mi] = *(const s16x8*)&sAlo[aidx[mi]];
        }
#pragma unroll
        for (int nj = 0; nj < 4; ++nj) {
            s16x8 bh = *(const s16x8*)&sBhi[bidx[nj]];
            s16x8 bl = *(const s16x8*)&sBlo[bidx[nj]];
#pragma unroll
            for (int mi = 0; mi < 4; ++mi) {
                acc[mi][nj] = __builtin_amdgcn_mfma_f32_16x16x32_bf16(ah[mi], bh, acc[mi][nj], 0, 0, 0);
                acc[mi][nj] = __builtin_amdgcn_mfma_f32_16x16x32_bf16(ah[mi], bl, acc[mi][nj], 0, 0, 0);
                acc[mi][nj] = __builtin_amdgcn_mfma_f32_16x16x32_bf16(al[mi], bh, acc[mi][nj], 0, 0, 0);
            }
        }
        __syncthreads();
    }

    int bg[4][4];
#pragma unroll
    for (int mi = 0; mi < 4; ++mi)
#pragma unroll
        for (int reg = 0; reg < 4; ++reg) {
            int r = row0 + wrow * 64 + mi * 16 + quad * 4 + reg;
            bg[mi][reg] = (r < Nrows) ? batch[r] : -1;
        }
    const int gfirst = batch[row0 < Nrows ? row0 : (Nrows - 1)];
    const int glast  = batch[min(row0 + 127, Nrows - 1)];

#pragma unroll
    for (int nj = 0; nj < 4; ++nj) {
        const int c = col0 + wcol * 64 + nj * 16 + l16;
        const float bc = bias[c];
        for (int g = gfirst; g <= glast; ++g) {
            float s = 0.f;
#pragma unroll
            for (int mi = 0; mi < 4; ++mi)
#pragma unroll
                for (int reg = 0; reg < 4; ++reg)
                    if (bg[mi][reg] == g) s += fmaxf(acc[mi][nj][reg] + bc, 0.f);
            s += __shfl_xor(s, 16);
            s += __shfl_xor(s, 32);
            if (quad == 0) atomicAdd(&gsum[g * 256 + c], s);
        }
    }
}

// ===================== aggregation: PAIRED-NODE waves (2x memory-level parallelism) ==
// Each wave processes TWO nodes with interleaved independent 8-deep unrolled edge
// loops -> up to 16 outstanding 1KB gathers per wave (was 8). Per-node FMA order
// unchanged => bit-identical. Dynamic HW block scheduling retained (6250 blocks).

// D=256: wave handles nodes va=base, vb=base+1; lane owns float4.
__global__ __launch_bounds__(256) void k_agg256(const float* __restrict__ H, const int* __restrict__ rowptr,
                                                const int* __restrict__ col, const float* __restrict__ nrm,
                                                const float* __restrict__ dinv,
                                                unsigned short* __restrict__ outHi,
                                                unsigned short* __restrict__ outLo, int N) {
    const int wave = threadIdx.x >> 6, lane = threadIdx.x & 63;
    const int va = blockIdx.x * 8 + wave * 2;
    const int vb = va + 1;
    if (va >= N) return;
    const bool hasb = (vb < N);

    const float dia = dinv[va];
    float4 ha = ((const float4*)&H[(size_t)va * 256])[lane];
    float ax = dia * dia * ha.x, ay = dia * dia * ha.y, az = dia * dia * ha.z, aw = dia * dia * ha.w;
    float bx = 0.f, by = 0.f, bz = 0.f, bw = 0.f;
    int eb = 0, endb = 0;
    if (hasb) {
        const float dib = dinv[vb];
        float4 hb = ((const float4*)&H[(size_t)vb * 256])[lane];
        bx = dib * dib * hb.x; by = dib * dib * hb.y; bz = dib * dib * hb.z; bw = dib * dib * hb.w;
        eb = rowptr[vb]; endb = rowptr[vb + 1];
    }
    int ea = rowptr[va];
    const int enda = rowptr[va + 1];

    // joint interleaved 8+8 main loop
    while (ea + 8 <= enda && eb + 8 <= endb) {
        int ua[8], ub[8]; float wa[8], wb[8]; float4 ga[8], gb[8];
#pragma unroll
        for (int j = 0; j < 8; ++j) { ua[j] = col[ea + j]; wa[j] = nrm[ea + j]; }
#pragma unroll
        for (int j = 0; j < 8; ++j) { ub[j] = col[eb + j]; wb[j] = nrm[eb + j]; }
#pragma unroll
        for (int j = 0; j < 8; ++j) ga[j] = ((const float4*)&H[(size_t)ua[j] * 256])[lane];
#pragma unroll
        for (int j = 0; j < 8; ++j) gb[j] = ((const float4*)&H[(size_t)ub[j] * 256])[lane];
#pragma unroll
        for (int j = 0; j < 8; ++j) {
            ax += wa[j] * ga[j].x; ay += wa[j] * ga[j].y; az += wa[j] * ga[j].z; aw += wa[j] * ga[j].w;
        }
#pragma unroll
        for (int j = 0; j < 8; ++j) {
            bx += wb[j] * gb[j].x; by += wb[j] * gb[j].y; bz += wb[j] * gb[j].z; bw += wb[j] * gb[j].w;
        }
        ea += 8; eb += 8;
    }
    // drain a
    for (; ea + 8 <= enda; ea += 8) {
        int u[8]; float w[8]; float4 g[8];
#pragma unroll
        for (int j = 0; j < 8; ++j) { u[j] = col[ea + j]; w[j] = nrm[ea + j]; }
#pragma unroll
        for (int j = 0; j < 8; ++j) g[j] = ((const float4*)&H[(size_t)u[j] * 256])[lane];
#pragma unroll
        for (int j = 0; j < 8; ++j) {
            ax += w[j] * g[j].x; ay += w[j] * g[j].y; az += w[j] * g[j].z; aw += w[j] * g[j].w;
        }
    }
    for (; ea < enda; ++ea) {
        const int u = col[ea]; const float w = nrm[ea];
        float4 g = ((const float4*)&H[(size_t)u * 256])[lane];
        ax += w * g.x; ay += w * g.y; az += w * g.z; aw += w * g.w;
    }
    // drain b
    for (; eb + 8 <= endb; eb += 8) {
        int u[8]; float w[8]; float4 g[8];
#pragma unroll
        for (int j = 0; j < 8; ++j) { u[j] = col[eb + j]; w[j] = nrm[eb + j]; }
#pragma unroll
        for (int j = 0; j < 8; ++j) g[j] = ((const float4*)&H[(size_t)u[j] * 256])[lane];
#pragma unroll
        for (int j = 0; j < 8; ++j) {
            bx += w[j] * g[j].x; by += w[j] * g[j].y; bz += w[j] * g[j].z; bw += w[j] * g[j].w;
        }
    }
    for (; eb < endb; ++eb) {
        const int u = col[eb]; const float w = nrm[eb];
        float4 g = ((const float4*)&H[(size_t)u * 256])[lane];
        bx += w * g.x; by += w * g.y; bz += w * g.z; bw += w * g.w;
    }

    ushort4 hi4, lo4;
    split2(ax, hi4.x, lo4.x); split2(ay, hi4.y, lo4.y);
    split2(az, hi4.z, lo4.z); split2(aw, hi4.w, lo4.w);
    ((ushort4*)outHi)[(size_t)va * 64 + lane] = hi4;
    ((ushort4*)outLo)[(size_t)va * 64 + lane] = lo4;
    if (hasb) {
        split2(bx, hi4.x, lo4.x); split2(by, hi4.y, lo4.y);
        split2(bz, hi4.z, lo4.z); split2(bw, hi4.w, lo4.w);
        ((ushort4*)outHi)[(size_t)vb * 64 + lane] = hi4;
        ((ushort4*)outLo)[(size_t)vb * 64 + lane] = lo4;
    }
}

// D=128: half-wave (32 lanes x float4 = 512B row) handles nodes va, vb; 4+4 unroll.
__global__ __launch_bounds__(256) void k_agg128(const float* __restrict__ X, const int* __restrict__ rowptr,
                                                const int* __restrict__ col, const float* __restrict__ nrm,
                                                const float* __restrict__ dinv,
                                                unsigned short* __restrict__ outHi,
                                                unsigned short* __restrict__ outLo, int N) {
    const int half = threadIdx.x >> 5, sub = threadIdx.x & 31;
    const int va = blockIdx.x * 16 + half * 2;
    const int vb = va + 1;
    if (va >= N) return;
    const bool hasb = (vb < N);

    const float dia = dinv[va];
    float4 ha = ((const float4*)&X[(size_t)va * 128])[sub];
    float ax = dia * dia * ha.x, ay = dia * dia * ha.y, az = dia * dia * ha.z, aw = dia * dia * ha.w;
    float bx = 0.f, by = 0.f, bz = 0.f, bw = 0.f;
    int eb = 0, endb = 0;
    if (hasb) {
        const float dib = dinv[vb];
        float4 hb = ((const float4*)&X[(size_t)vb * 128])[sub];
        bx = dib * dib * hb.x; by = dib * dib * hb.y; bz = dib * dib * hb.z; bw = dib * dib * hb.w;
        eb = rowptr[vb]; endb = rowptr[vb + 1];
    }
    int ea = rowptr[va];
    const int enda = rowptr[va + 1];

    while (ea + 4 <= enda && eb + 4 <= endb) {
        int ua[4], ub[4]; float wa[4], wb[4]; float4 ga[4], gb[4];
#pragma unroll
        for (int j = 0; j < 4; ++j) { ua[j] = col[ea + j]; wa[j] = nrm[ea + j]; }
#pragma unroll
        for (int j = 0; j < 4; ++j) { ub[j] = col[eb + j]; wb[j] = nrm[eb + j]; }
#pragma unroll
        for (int j = 0; j < 4; ++j) ga[j] = ((const float4*)&X[(size_t)ua[j] * 128])[sub];
#pragma unroll
        for (int j = 0; j < 4; ++j) gb[j] = ((const float4*)&X[(size_t)ub[j] * 128])[sub];
#pragma unroll
        for (int j = 0; j < 4; ++j) {
            ax += wa[j] * ga[j].x; ay += wa[j] * ga[j].y; az += wa[j] * ga[j].z; aw += wa[j] * ga[j].w;
        }
#pragma unroll
        for (int j = 0; j < 4; ++j) {
            bx += wb[j] * gb[j].x; by += wb[j] * gb[j].y; bz += wb[j] * gb[j].z; bw += wb[j] * gb[j].w;
        }
        ea += 4; eb += 4;
    }
    for (; ea + 4 <= enda; ea += 4) {
        int u[4]; float w[4]; float4 g[4];
#pragma unroll
        for (int j = 0; j < 4; ++j) { u[j] = col[ea + j]; w[j] = nrm[ea + j]; }
#pragma unroll
        for (int j = 0; j < 4; ++j) g[j] = ((const float4*)&X[(size_t)u[j] * 128])[sub];
#pragma unroll
        for (int j = 0; j < 4; ++j) {
            ax += w[j] * g[j].x; ay += w[j] * g[j].y; az += w[j] * g[j].z; aw += w[j] * g[j].w;
        }
    }
    for (; ea < enda; ++ea) {
        const int u = col[ea]; const float w = nrm[ea];
        float4 g = ((const float4*)&X[(size_t)u * 128])[sub];
        ax += w * g.x; ay += w * g.y; az += w * g.z; aw += w * g.w;
    }
    for (; eb + 4 <= endb; eb += 4) {
        int u[4]; float w[4]; float4 g[4];
#pragma unroll
        for (int j = 0; j < 4; ++j) { u[j] = col[eb + j]; w[j] = nrm[eb + j]; }
#pragma unroll
        for (int j = 0; j < 4; ++j) g[j] = ((const float4*)&X[(size_t)u[j] * 128])[sub];
#pragma unroll
        for (int j = 0; j < 4; ++j) {
            bx += w[j] * g[j].x; by += w[j] * g[j].y; bz += w[j] * g[j].z; bw += w[j] * g[j].w;
        }
    }
    for (; eb < endb; ++eb) {
        const int u = col[eb]; const float w = nrm[eb];
        float4 g = ((const float4*)&X[(size_t)u * 128])[sub];
        bx += w * g.x; by += w * g.y; bz += w * g.z; bw += w * g.w;
    }

    ushort4 hi4, lo4;
    split2(ax, hi4.x, lo4.x); split2(ay, hi4.y, lo4.y);
    split2(az, hi4.z, lo4.z); split2(aw, hi4.w, lo4.w);
    ((ushort4*)outHi)[(size_t)va * 32 + sub] = hi4;
    ((ushort4*)outLo)[(size_t)va * 32 + sub] = lo4;
    if (hasb) {
        split2(bx, hi4.x, lo4.x); split2(by, hi4.y, lo4.y);
        split2(bz, hi4.z, lo4.z); split2(bw, hi4.w, lo4.w);
        ((ushort4*)outHi)[(size_t)vb * 32 + sub] = hi4;
        ((ushort4*)outLo)[(size_t)vb * 32 + sub] = lo4;
    }
}

// ===================== fused mean-pool finalize + classifier head =====================

__global__ __launch_bounds__(256) void k_poolcls(const float* __restrict__ gsum, const int* __restrict__ gstart,
                                                 const float* __restrict__ Wc1, const float* __restrict__ bc1,
                                                 const float* __restrict__ Wc2, const float* __restrict__ bc2,
                                                 float* __restrict__ out) {
    __shared__ float sg[256], sh[256];
    const int b = blockIdx.x, t = threadIdx.x;
    const float c = (float)(gstart[b + 1] - gstart[b]);
    sg[t] = gsum[b * 256 + t] / fmaxf(c, 1.0f);
    __syncthreads();
    float acc = bc1[t];
    for (int k = 0; k < 256; ++k) acc += sg[k] * Wc1[k * 256 + t];
    sh[t] = fmaxf(acc, 0.f);
    __syncthreads();
    if (t < 5) {
        float o = bc2[t];
        for (int k = 0; k < 256; ++k) o += sh[k] * Wc2[k * 5 + t];
        out[b * 5 + t] = o;
    }
}

// ===================== launch =====================

extern "C" void kernel_launch(void* const* d_in, const int* in_sizes, int n_in,
                              void* d_out, int out_size, void* d_ws, size_t ws_size,
                              hipStream_t stream) {
    const float* x    = (const float*)d_in[0];
    const int*   eidx = (const int*)d_in[1];
    const int*   batch= (const int*)d_in[2];
    const float* W0 = (const float*)d_in[3];  const float* b0 = (const float*)d_in[4];
    const float* W1 = (const float*)d_in[5];  const float* b1 = (const float*)d_in[6];
    const float* W2 = (const float*)d_in[7];  const float* b2 = (const float*)d_in[8];
    const float* Wc1= (const float*)d_in[9];  const float* bc1= (const float*)d_in[10];
    const float* Wc2= (const float*)d_in[11]; const float* bc2= (const float*)d_in[12];
    float* out = (float*)d_out;

    const int N   = in_sizes[2];       // 50000
    const int E   = in_sizes[1] / 2;   // 500000
    const int DIN = in_sizes[0] / N;   // 128
    const int DH  = in_sizes[4];       // 256
    const int* src = eidx;
    const int* dst = eidx + E;

    char* p = (char*)d_ws;
    auto alloc = [&](size_t bytes) {
        char* r = p;
        p += (bytes + 255) & ~(size_t)255;
        return (void*)r;
    };
    float*          hbuf = (float*)alloc((size_t)N * DH * 4);
    unsigned short* hhi  = (unsigned short*)alloc((size_t)N * DH * 2);
    unsigned short* hlo  = (unsigned short*)alloc((size_t)N * DH * 2);
    unsigned short* w0hi = (unsigned short*)alloc((size_t)DH * DIN * 2);
    unsigned short* w0lo = (unsigned short*)alloc((size_t)DH * DIN * 2);
    unsigned short* w1hi = (unsigned short*)alloc((size_t)DH * DH * 2);
    unsigned short* w1lo = (unsigned short*)alloc((size_t)DH * DH * 2);
    unsigned short* w2hi = (unsigned short*)alloc((size_t)DH * DH * 2);
    unsigned short* w2lo = (unsigned short*)alloc((size_t)DH * DH * 2);
    int*   deg   = (int*)alloc((size_t)N * 4);
    float* gsum  = (float*)alloc(64 * (size_t)DH * 4);   // adjacent to deg: one memset covers both
    float* dinv  = (float*)alloc((size_t)N * 4);
    int*   part  = (int*)alloc((size_t)N * 4);
    int*   bsum  = (int*)alloc(256 * 4);
    int*   rowptr= (int*)alloc((size_t)(N + 1) * 4);
    int*   cursor= (int*)alloc((size_t)N * 4);
    int*   col   = (int*)alloc((size_t)E * 4);
    float* nrm   = (float*)alloc((size_t)E * 4);
    int*   gstart= (int*)alloc(65 * 4);

    hipMemsetAsync(deg, 0, (size_t)((char*)gsum - (char*)deg) + 64 * (size_t)DH * 4, stream);

    const int nb = (N + 255) / 256;
    const int wtot = DIN * DH + 2 * DH * DH;
    const int wb = (wtot + 255) / 256;

    k_deg   <<<(E + 255) / 256, 256, 0, stream>>>(dst, E, deg);
    k_scan1w<<<nb + wb, 256, 0, stream>>>(deg, N, nb, part, bsum, dinv,
                                          W0, w0hi, w0lo, W1, w1hi, w1lo, W2, w2hi, w2lo, DIN, DH);
    k_scan2 <<<1, 256, 0, stream>>>(bsum, nb, batch, N, 64, gstart);
    k_scan3 <<<nb, 256, 0, stream>>>(part, bsum, N, E, rowptr, cursor);
    k_fill  <<<(E + 255) / 256, 256, 0, stream>>>(src, dst, E, dinv, cursor, col, nrm);

    dim3 gemmGrid(DH / 128, (N + 127) / 128);

    // layer 0
    k_agg128<<<(N + 15) / 16, 256, 0, stream>>>(x, rowptr, col, nrm, dinv, hhi, hlo, N);
    k_gemm_mfma<<<gemmGrid, 256, 0, stream>>>(hhi, hlo, w0hi, w0lo, b0, hbuf, N, DIN);
    // layer 1
    k_agg256<<<(N + 7) / 8, 256, 0, stream>>>(hbuf, rowptr, col, nrm, dinv, hhi, hlo, N);
    k_gemm_mfma<<<gemmGrid, 256, 0, stream>>>(hhi, hlo, w1hi, w1lo, b1, hbuf, N, DH);
    // layer 2 (fused pooling epilogue)
    k_agg256<<<(N + 7) / 8, 256, 0, stream>>>(hbuf, rowptr, col, nrm, dinv, hhi, hlo, N);
    k_gemm_pool<<<gemmGrid, 256, 0, stream>>>(hhi, hlo, w2hi, w2lo, b2, batch, gsum, N, DH);

    k_poolcls<<<64, 256, 0, stream>>>(gsum, gstart, Wc1, bc1, Wc2, bc2, out);
}

// Round 12
// 397.315 us; speedup vs baseline: 1.2091x; 1.2091x over previous
//
#include <hip/hip_runtime.h>
#include <hip/hip_fp16.h>

typedef short s16x8 __attribute__((ext_vector_type(8)));   // 8 bf16 = 4 VGPRs
typedef float fx4 __attribute__((ext_vector_type(4)));     // MFMA acc

#define AS_G(p) ((const __attribute__((address_space(1))) void*)(p))
#define AS_L(p) ((__attribute__((address_space(3))) void*)(p))

struct __align__(8) half4 { __half2 lo, hi; };

__device__ inline unsigned short f32_to_bf16(float f) {
    unsigned int u = __float_as_uint(f);
    return (unsigned short)((u + 0x7fffu + ((u >> 16) & 1u)) >> 16);
}
__device__ inline float bf16_to_f32(unsigned short b) {
    return __uint_as_float(((unsigned int)b) << 16);
}
__device__ inline void split2(float a, unsigned short& hi, unsigned short& lo) {
    hi = f32_to_bf16(a);
    lo = f32_to_bf16(a - bf16_to_f32(hi));
}

// ===================== graph preprocessing =====================

// fused dispatch: blocks [0,degB) histogram degrees; blocks [degB,..) convert x -> fp16.
__global__ void k_degx(const int* __restrict__ dst, int E, int* __restrict__ deg, int degB,
                       const float* __restrict__ x, __half* __restrict__ xh, int nx) {
    if (blockIdx.x < (unsigned)degB) {
        int i = blockIdx.x * 256 + threadIdx.x;
        if (i < E) atomicAdd(&deg[dst[i]], 1);
    } else {
        int i = (blockIdx.x - degB) * 1024 + threadIdx.x * 4;
        if (i < nx) {
            float4 v = *(const float4*)&x[i];
            __half2 h0(__float2half(v.x), __float2half(v.y));
            __half2 h1(__float2half(v.z), __float2half(v.w));
            *(__half2*)&xh[i] = h0;
            *(__half2*)&xh[i + 2] = h1;
        }
    }
}

// fused dispatch: blocks [0,nb) do deg-scan + dinv; blocks [nb,..) split/transpose weights.
__global__ void k_scan1w(const int* __restrict__ deg, int N, int nb,
                         int* __restrict__ part, int* __restrict__ bsum, float* __restrict__ dinv,
                         const float* __restrict__ W0, unsigned short* __restrict__ h0, unsigned short* __restrict__ l0,
                         const float* __restrict__ W1, unsigned short* __restrict__ h1, unsigned short* __restrict__ l1,
                         const float* __restrict__ W2, unsigned short* __restrict__ h2, unsigned short* __restrict__ l2,
                         int DIN, int DH) {
    __shared__ int s[256];
    if (blockIdx.x < (unsigned)nb) {
        int i = blockIdx.x * 256 + threadIdx.x;
        int v = (i < N) ? deg[i] : 0;
        if (i < N) dinv[i] = 1.0f / sqrtf((float)(v + 1));  // +1 self-loop
        s[threadIdx.x] = v;
        __syncthreads();
        for (int off = 1; off < 256; off <<= 1) {
            int t = (threadIdx.x >= off) ? s[threadIdx.x - off] : 0;
            __syncthreads();
            s[threadIdx.x] += t;
            __syncthreads();
        }
        if (i < N) part[i] = s[threadIdx.x] - v;
        if (threadIdx.x == 255) bsum[blockIdx.x] = s[255];
    } else {
        int i = (blockIdx.x - nb) * 256 + threadIdx.x;
        const int n0 = DIN * DH, n1 = DH * DH;
        const float* W; unsigned short *hT, *lT; int K, li;
        if (i < n0) { W = W0; hT = h0; lT = l0; K = DIN; li = i; }
        else if (i < n0 + n1) { W = W1; hT = h1; lT = l1; K = DH; li = i - n0; }
        else if (i < n0 + 2 * n1) { W = W2; hT = h2; lT = l2; K = DH; li = i - n0 - n1; }
        else return;
        int k = li / DH, n = li - k * DH;
        unsigned short h, l;
        split2(W[li], h, l);
        hT[(size_t)n * K + k] = h;
        lT[(size_t)n * K + k] = l;
    }
}

// fused: scan of block sums + graph-boundary binary search over sorted batch
__global__ void k_scan2(int* __restrict__ bsum, int nb,
                        const int* __restrict__ batch, int N, int ngraphs, int* __restrict__ gstart) {
    int g = threadIdx.x;
    if (g <= ngraphs) {
        if (g == ngraphs) gstart[g] = N;
        else {
            int lo = 0, hi = N;
            while (lo < hi) {
                int mid = (lo + hi) >> 1;
                if (batch[mid] < g) lo = mid + 1; else hi = mid;
            }
            gstart[g] = lo;
        }
    }
    __shared__ int s[256];
    int v = (threadIdx.x < nb) ? bsum[threadIdx.x] : 0;
    s[threadIdx.x] = v;
    __syncthreads();
    for (int off = 1; off < 256; off <<= 1) {
        int t = (threadIdx.x >= off) ? s[threadIdx.x - off] : 0;
        __syncthreads();
        s[threadIdx.x] += t;
        __syncthreads();
    }
    if (threadIdx.x < nb) bsum[threadIdx.x] = s[threadIdx.x] - v;
}

__global__ void k_scan3(const int* __restrict__ part, const int* __restrict__ bsum, int N, int E,
                        int* __restrict__ rowptr, int* __restrict__ cursor) {
    int i = blockIdx.x * 256 + threadIdx.x;
    if (i < N) {
        int v = part[i] + bsum[blockIdx.x];
        rowptr[i] = v;
        cursor[i] = v;
    }
    if (i == 0) rowptr[N] = E;
}

__global__ void k_fill(const int* __restrict__ src, const int* __restrict__ dst, int E,
                       const float* __restrict__ dinv, int* __restrict__ cursor,
                       int* __restrict__ col, float* __restrict__ nrm) {
    int e = blockIdx.x * blockDim.x + threadIdx.x;
    if (e < E) {
        int s = src[e], d = dst[e];
        int p = atomicAdd(&cursor[d], 1);
        col[p] = s;
        nrm[p] = dinv[s] * dinv[d];
    }
}

// ===================== split-bf16 MFMA GEMM + fused bias/ReLU, fp16 out =====================
// C[N x 256] = relu(A @ B + bias) stored as fp16 (next consumer is the gather, which
// only needs ~2^-11 precision; halves both write and gather traffic).

__global__ __launch_bounds__(256) void k_gemm_mfma(
    const unsigned short* __restrict__ Ahi, const unsigned short* __restrict__ Alo,
    const unsigned short* __restrict__ BhiT, const unsigned short* __restrict__ BloT,
    const float* __restrict__ bias, __half* __restrict__ C, int Nrows, int K) {
    __shared__ __align__(16) unsigned short sAhi[128 * 32];
    __shared__ __align__(16) unsigned short sAlo[128 * 32];
    __shared__ __align__(16) unsigned short sBhi[128 * 32];
    __shared__ __align__(16) unsigned short sBlo[128 * 32];

    const int tid = threadIdx.x;
    const int wid = tid >> 6, lane = tid & 63;
    const int row0 = blockIdx.y * 128;
    const int col0 = blockIdx.x * 128;
    const int wrow = wid & 1, wcol = wid >> 1;
    const int quad = lane >> 4, l16 = lane & 15;

    const unsigned short* garr = (wid == 0) ? Ahi : (wid == 1) ? Alo : (wid == 2) ? BhiT : BloT;
    unsigned short* sarr = (wid == 0) ? sAhi : (wid == 1) ? sAlo : (wid == 2) ? sBhi : sBlo;
    const bool isA = (wid < 2);

    const unsigned short* gp[8];
#pragma unroll
    for (int i = 0; i < 8; ++i) {
        int r = 16 * i + (lane >> 2);
        int s = lane & 3;
        int q = (s - (r >> 1)) & 3;              // XOR bank-swizzle in global address
        int grow = isA ? min(row0 + r, Nrows - 1) : (col0 + r);
        gp[i] = garr + (size_t)grow * K + q * 8;
    }

    int aidx[4], bidx[4];
#pragma unroll
    for (int t = 0; t < 4; ++t) {
        int ra = wrow * 64 + t * 16 + l16;
        aidx[t] = ra * 32 + ((quad + (ra >> 1)) & 3) * 8;
        int rb = wcol * 64 + t * 16 + l16;
        bidx[t] = rb * 32 + ((quad + (rb >> 1)) & 3) * 8;
    }

    fx4 acc[4][4] = {};

    for (int k0 = 0; k0 < K; k0 += 32) {
#pragma unroll
        for (int i = 0; i < 8; ++i)
            __builtin_amdgcn_global_load_lds(AS_G(gp[i] + k0), AS_L((char*)sarr + i * 1024), 16, 0, 0);
        __syncthreads();

        s16x8 ah[4], al[4];
#pragma unroll
        for (int mi = 0; mi < 4; ++mi) {
            ah[mi] = *(const s16x8*)&sAhi[aidx[mi]];
            al[mi] = *(const s16x8*)&sAlo[aidx[mi]];
        }
#pragma unroll
        for (int nj = 0; nj < 4; ++nj) {
            s16x8 bh = *(const s16x8*)&sBhi[bidx[nj]];
            s16x8 bl = *(const s16x8*)&sBlo[bidx[nj]];
#pragma unroll
            for (int mi = 0; mi < 4; ++mi) {
                acc[mi][nj] = __builtin_amdgcn_mfma_f32_16x16x32_bf16(ah[mi], bh, acc[mi][nj], 0, 0, 0);
                acc[mi][nj] = __builtin_amdgcn_mfma_f32_16x16x32_bf16(ah[mi], bl, acc[mi][nj], 0, 0, 0);
                acc[mi][nj] = __builtin_amdgcn_mfma_f32_16x16x32_bf16(al[mi], bh, acc[mi][nj], 0, 0, 0);
            }
        }
        __syncthreads();
    }

    // C/D layout: col = lane&15, row = quad*4 + reg  [m89-verified]
#pragma unroll
    for (int mi = 0; mi < 4; ++mi) {
        const int rbase = row0 + wrow * 64 + mi * 16 + quad * 4;
#pragma unroll
        for (int nj = 0; nj < 4; ++nj) {
            const int c = col0 + wcol * 64 + nj * 16 + l16;
            const float bc = bias[c];
#pragma unroll
            for (int reg = 0; reg < 4; ++reg) {
                int r = rbase + reg;
                if (r < Nrows) C[(size_t)r * 256 + c] = __float2half(fmaxf(acc[mi][nj][reg] + bc, 0.f));
            }
        }
    }
}

// Layer-2 variant: relu(acc+bias) pooled per-graph into gsum[64][256] via segment
// reduction + cross-quad shfl + atomicAdd (batch sorted => few segments per tile).
__global__ __launch_bounds__(256) void k_gemm_pool(
    const unsigned short* __restrict__ Ahi, const unsigned short* __restrict__ Alo,
    const unsigned short* __restrict__ BhiT, const unsigned short* __restrict__ BloT,
    const float* __restrict__ bias, const int* __restrict__ batch,
    float* __restrict__ gsum, int Nrows, int K) {
    __shared__ __align__(16) unsigned short sAhi[128 * 32];
    __shared__ __align__(16) unsigned short sAlo[128 * 32];
    __shared__ __align__(16) unsigned short sBhi[128 * 32];
    __shared__ __align__(16) unsigned short sBlo[128 * 32];

    const int tid = threadIdx.x;
    const int wid = tid >> 6, lane = tid & 63;
    const int row0 = blockIdx.y * 128;
    const int col0 = blockIdx.x * 128;
    const int wrow = wid & 1, wcol = wid >> 1;
    const int quad = lane >> 4, l16 = lane & 15;

    const unsigned short* garr = (wid == 0) ? Ahi : (wid == 1) ? Alo : (wid == 2) ? BhiT : BloT;
    unsigned short* sarr = (wid == 0) ? sAhi : (wid == 1) ? sAlo : (wid == 2) ? sBhi : sBlo;
    const bool isA = (wid < 2);

    const unsigned short* gp[8];
#pragma unroll
    for (int i = 0; i < 8; ++i) {
        int r = 16 * i + (lane >> 2);
        int s = lane & 3;
        int q = (s - (r >> 1)) & 3;
        int grow = isA ? min(row0 + r, Nrows - 1) : (col0 + r);
        gp[i] = garr + (size_t)grow * K + q * 8;
    }

    int aidx[4], bidx[4];
#pragma unroll
    for (int t = 0; t < 4; ++t) {
        int ra = wrow * 64 + t * 16 + l16;
        aidx[t] = ra * 32 + ((quad + (ra >> 1)) & 3) * 8;
        int rb = wcol * 64 + t * 16 + l16;
        bidx[t] = rb * 32 + ((quad + (rb >> 1)) & 3) * 8;
    }

    fx4 acc[4][4] = {};

    for (int k0 = 0; k0 < K; k0 += 32) {
#pragma unroll
        for (int i = 0; i < 8; ++i)
            __builtin_amdgcn_global_load_lds(AS_G(gp[i] + k0), AS_L((char*)sarr + i * 1024), 16, 0, 0);
        __syncthreads();

        s16x8 ah[4], al[4];
#pragma unroll
        for (int mi = 0; mi < 4; ++mi) {
            ah[mi] = *(const s16x8*)&sAhi[aidx[mi]];
            al[mi] = *(const s16x8*)&sAlo[aidx[mi]];
        }
#pragma unroll
        for (int nj = 0; nj < 4; ++nj) {
            s16x8 bh = *(const s16x8*)&sBhi[bidx[nj]];
            s16x8 bl = *(const s16x8*)&sBlo[bidx[nj]];
#pragma unroll
            for (int mi = 0; mi < 4; ++mi) {
                acc[mi][nj] = __builtin_amdgcn_mfma_f32_16x16x32_bf16(ah[mi], bh, acc[mi][nj], 0, 0, 0);
                acc[mi][nj] = __builtin_amdgcn_mfma_f32_16x16x32_bf16(ah[mi], bl, acc[mi][nj], 0, 0, 0);
                acc[mi][nj] = __builtin_amdgcn_mfma_f32_16x16x32_bf16(al[mi], bh, acc[mi][nj], 0, 0, 0);
            }
        }
        __syncthreads();
    }

    int bg[4][4];
#pragma unroll
    for (int mi = 0; mi < 4; ++mi)
#pragma unroll
        for (int reg = 0; reg < 4; ++reg) {
            int r = row0 + wrow * 64 + mi * 16 + quad * 4 + reg;
            bg[mi][reg] = (r < Nrows) ? batch[r] : -1;
        }
    const int gfirst = batch[row0 < Nrows ? row0 : (Nrows - 1)];
    const int glast  = batch[min(row0 + 127, Nrows - 1)];

#pragma unroll
    for (int nj = 0; nj < 4; ++nj) {
        const int c = col0 + wcol * 64 + nj * 16 + l16;
        const float bc = bias[c];
        for (int g = gfirst; g <= glast; ++g) {
            float s = 0.f;
#pragma unroll
            for (int mi = 0; mi < 4; ++mi)
#pragma unroll
                for (int reg = 0; reg < 4; ++reg)
                    if (bg[mi][reg] == g) s += fmaxf(acc[mi][nj][reg] + bc, 0.f);
            s += __shfl_xor(s, 16);
            s += __shfl_xor(s, 32);
            if (quad == 0) atomicAdd(&gsum[g * 256 + c], s);
        }
    }
}

// ===================== aggregation (fp16 gather, fp32 accumulate) =====================
// WAVE-PER-NODE (best measured form; r8 scheduling + r11 ILP variants both neutral —
// the gather is fabric-limited, so the lever is bytes: fp16 rows halve traffic).

// D=256: wave per node, lane owns half4 (8B); 8 gathers in flight.
__global__ __launch_bounds__(256) void k_agg256(const __half* __restrict__ H, const int* __restrict__ rowptr,
                                                const int* __restrict__ col, const float* __restrict__ nrm,
                                                const float* __restrict__ dinv,
                                                unsigned short* __restrict__ outHi,
                                                unsigned short* __restrict__ outLo, int N) {
    const int wave = threadIdx.x >> 6, lane = threadIdx.x & 63;
    const int v = blockIdx.x * 4 + wave;
    if (v >= N) return;

    const float di = dinv[v];
    const float selfn = di * di;
    half4 hv = ((const half4*)&H[(size_t)v * 256])[lane];
    float2 s0 = __half22float2(hv.lo), s1 = __half22float2(hv.hi);
    float ax = selfn * s0.x, ay = selfn * s0.y, az = selfn * s1.x, aw = selfn * s1.y;

    int e = rowptr[v];
    const int end = rowptr[v + 1];
    for (; e + 8 <= end; e += 8) {
        int u[8]; float w[8]; half4 g[8];
#pragma unroll
        for (int j = 0; j < 8; ++j) { u[j] = col[e + j]; w[j] = nrm[e + j]; }
#pragma unroll
        for (int j = 0; j < 8; ++j) g[j] = ((const half4*)&H[(size_t)u[j] * 256])[lane];
#pragma unroll
        for (int j = 0; j < 8; ++j) {
            float2 f0 = __half22float2(g[j].lo), f1 = __half22float2(g[j].hi);
            ax += w[j] * f0.x; ay += w[j] * f0.y; az += w[j] * f1.x; aw += w[j] * f1.y;
        }
    }
    for (; e < end; ++e) {
        const int u = col[e];
        const float w = nrm[e];
        half4 g = ((const half4*)&H[(size_t)u * 256])[lane];
        float2 f0 = __half22float2(g.lo), f1 = __half22float2(g.hi);
        ax += w * f0.x; ay += w * f0.y; az += w * f1.x; aw += w * f1.y;
    }

    ushort4 hi4, lo4;
    split2(ax, hi4.x, lo4.x);
    split2(ay, hi4.y, lo4.y);
    split2(az, hi4.z, lo4.z);
    split2(aw, hi4.w, lo4.w);
    ((ushort4*)outHi)[(size_t)v * 64 + lane] = hi4;
    ((ushort4*)outLo)[(size_t)v * 64 + lane] = lo4;
}

// D=128: half-wave per node on fp16 x (256B rows), lane owns half4; 4-deep unroll.
__global__ __launch_bounds__(256) void k_agg128(const __half* __restrict__ X, const int* __restrict__ rowptr,
                                                const int* __restrict__ col, const float* __restrict__ nrm,
                                                const float* __restrict__ dinv,
                                                unsigned short* __restrict__ outHi,
                                                unsigned short* __restrict__ outLo, int N) {
    const int half = threadIdx.x >> 5, sub = threadIdx.x & 31;
    const int v = blockIdx.x * 8 + half;
    if (v >= N) return;

    const float di = dinv[v];
    const float selfn = di * di;
    half4 hv = ((const half4*)&X[(size_t)v * 128])[sub];
    float2 s0 = __half22float2(hv.lo), s1 = __half22float2(hv.hi);
    float ax = selfn * s0.x, ay = selfn * s0.y, az = selfn * s1.x, aw = selfn * s1.y;

    int e = rowptr[v];
    const int end = rowptr[v + 1];
    for (; e + 4 <= end; e += 4) {
        int u[4]; float w[4]; half4 g[4];
#pragma unroll
        for (int j = 0; j < 4; ++j) { u[j] = col[e + j]; w[j] = nrm[e + j]; }
#pragma unroll
        for (int j = 0; j < 4; ++j) g[j] = ((const half4*)&X[(size_t)u[j] * 128])[sub];
#pragma unroll
        for (int j = 0; j < 4; ++j) {
            float2 f0 = __half22float2(g[j].lo), f1 = __half22float2(g[j].hi);
            ax += w[j] * f0.x; ay += w[j] * f0.y; az += w[j] * f1.x; aw += w[j] * f1.y;
        }
    }
    for (; e < end; ++e) {
        const int u = col[e];
        const float w = nrm[e];
        half4 g = ((const half4*)&X[(size_t)u * 128])[sub];
        float2 f0 = __half22float2(g.lo), f1 = __half22float2(g.hi);
        ax += w * f0.x; ay += w * f0.y; az += w * f1.x; aw += w * f1.y;
    }

    ushort4 hi4, lo4;
    split2(ax, hi4.x, lo4.x);
    split2(ay, hi4.y, lo4.y);
    split2(az, hi4.z, lo4.z);
    split2(aw, hi4.w, lo4.w);
    ((ushort4*)outHi)[(size_t)v * 32 + sub] = hi4;
    ((ushort4*)outLo)[(size_t)v * 32 + sub] = lo4;
}

// ===================== fused mean-pool finalize + classifier head =====================

__global__ __launch_bounds__(256) void k_poolcls(const float* __restrict__ gsum, const int* __restrict__ gstart,
                                                 const float* __restrict__ Wc1, const float* __restrict__ bc1,
                                                 const float* __restrict__ Wc2, const float* __restrict__ bc2,
                                                 float* __restrict__ out) {
    __shared__ float sg[256], sh[256];
    const int b = blockIdx.x, t = threadIdx.x;
    const float c = (float)(gstart[b + 1] - gstart[b]);
    sg[t] = gsum[b * 256 + t] / fmaxf(c, 1.0f);
    __syncthreads();
    float acc = bc1[t];
    for (int k = 0; k < 256; ++k) acc += sg[k] * Wc1[k * 256 + t];
    sh[t] = fmaxf(acc, 0.f);
    __syncthreads();
    if (t < 5) {
        float o = bc2[t];
        for (int k = 0; k < 256; ++k) o += sh[k] * Wc2[k * 5 + t];
        out[b * 5 + t] = o;
    }
}

// ===================== launch =====================

extern "C" void kernel_launch(void* const* d_in, const int* in_sizes, int n_in,
                              void* d_out, int out_size, void* d_ws, size_t ws_size,
                              hipStream_t stream) {
    const float* x    = (const float*)d_in[0];
    const int*   eidx = (const int*)d_in[1];
    const int*   batch= (const int*)d_in[2];
    const float* W0 = (const float*)d_in[3];  const float* b0 = (const float*)d_in[4];
    const float* W1 = (const float*)d_in[5];  const float* b1 = (const float*)d_in[6];
    const float* W2 = (const float*)d_in[7];  const float* b2 = (const float*)d_in[8];
    const float* Wc1= (const float*)d_in[9];  const float* bc1= (const float*)d_in[10];
    const float* Wc2= (const float*)d_in[11]; const float* bc2= (const float*)d_in[12];
    float* out = (float*)d_out;

    const int N   = in_sizes[2];       // 50000
    const int E   = in_sizes[1] / 2;   // 500000
    const int DIN = in_sizes[0] / N;   // 128
    const int DH  = in_sizes[4];       // 256
    const int* src = eidx;
    const int* dst = eidx + E;

    char* p = (char*)d_ws;
    auto alloc = [&](size_t bytes) {
        char* r = p;
        p += (bytes + 255) & ~(size_t)255;
        return (void*)r;
    };
    __half*         hbuf = (__half*)alloc((size_t)N * DH * 2);          // gemm out (fp16), agg gather in
    __half*         xh   = (__half*)alloc((size_t)N * DIN * 2);         // x in fp16
    unsigned short* hhi  = (unsigned short*)alloc((size_t)N * DH * 2);  // agg split out / gemm A in
    unsigned short* hlo  = (unsigned short*)alloc((size_t)N * DH * 2);
    unsigned short* w0hi = (unsigned short*)alloc((size_t)DH * DIN * 2);
    unsigned short* w0lo = (unsigned short*)alloc((size_t)DH * DIN * 2);
    unsigned short* w1hi = (unsigned short*)alloc((size_t)DH * DH * 2);
    unsigned short* w1lo = (unsigned short*)alloc((size_t)DH * DH * 2);
    unsigned short* w2hi = (unsigned short*)alloc((size_t)DH * DH * 2);
    unsigned short* w2lo = (unsigned short*)alloc((size_t)DH * DH * 2);
    int*   deg   = (int*)alloc((size_t)N * 4);
    float* gsum  = (float*)alloc(64 * (size_t)DH * 4);   // adjacent to deg: one memset covers both
    float* dinv  = (float*)alloc((size_t)N * 4);
    int*   part  = (int*)alloc((size_t)N * 4);
    int*   bsum  = (int*)alloc(256 * 4);
    int*   rowptr= (int*)alloc((size_t)(N + 1) * 4);
    int*   cursor= (int*)alloc((size_t)N * 4);
    int*   col   = (int*)alloc((size_t)E * 4);
    float* nrm   = (float*)alloc((size_t)E * 4);
    int*   gstart= (int*)alloc(65 * 4);

    hipMemsetAsync(deg, 0, (size_t)((char*)gsum - (char*)deg) + 64 * (size_t)DH * 4, stream);

    const int nb = (N + 255) / 256;
    const int wtot = DIN * DH + 2 * DH * DH;
    const int wb = (wtot + 255) / 256;
    const int degB = (E + 255) / 256;
    const int nx = N * DIN;
    const int xb = (nx + 1023) / 1024;

    k_degx  <<<degB + xb, 256, 0, stream>>>(dst, E, deg, degB, x, xh, nx);
    k_scan1w<<<nb + wb, 256, 0, stream>>>(deg, N, nb, part, bsum, dinv,
                                          W0, w0hi, w0lo, W1, w1hi, w1lo, W2, w2hi, w2lo, DIN, DH);
    k_scan2 <<<1, 256, 0, stream>>>(bsum, nb, batch, N, 64, gstart);
    k_scan3 <<<nb, 256, 0, stream>>>(part, bsum, N, E, rowptr, cursor);
    k_fill  <<<(E + 255) / 256, 256, 0, stream>>>(src, dst, E, dinv, cursor, col, nrm);

    dim3 gemmGrid(DH / 128, (N + 127) / 128);

    // layer 0: agg(x fp16) -> gemm(relu(.W0+b0)) -> fp16 H
    k_agg128<<<(N + 7) / 8, 256, 0, stream>>>(xh, rowptr, col, nrm, dinv, hhi, hlo, N);
    k_gemm_mfma<<<gemmGrid, 256, 0, stream>>>(hhi, hlo, w0hi, w0lo, b0, hbuf, N, DIN);
    // layer 1
    k_agg256<<<(N + 3) / 4, 256, 0, stream>>>(hbuf, rowptr, col, nrm, dinv, hhi, hlo, N);
    k_gemm_mfma<<<gemmGrid, 256, 0, stream>>>(hhi, hlo, w1hi, w1lo, b1, hbuf, N, DH);
    // layer 2 (fused pooling epilogue)
    k_agg256<<<(N + 3) / 4, 256, 0, stream>>>(hbuf, rowptr, col, nrm, dinv, hhi, hlo, N);
    k_gemm_pool<<<gemmGrid, 256, 0, stream>>>(hhi, hlo, w2hi, w2lo, b2, batch, gsum, N, DH);

    k_poolcls<<<64, 256, 0, stream>>>(gsum, gstart, Wc1, bc1, Wc2, bc2, out);
}